// Round 13
// baseline (155.698 us; speedup 1.0000x reference)
//
#include <hip/hip_runtime.h>

// TFLite STFT as bf16 MFMA GEMM. Output: real part only,
// out[(b*2397+f)*401+k], 15,379,152 floats.
// Round 13: wave tile 64f x 64k (16 MFMA per 8KB of L2 loads, was 8 per 6KB)
// at unchanged grid 7x19x16 with XCD swizzle; prep kernels fused into one.

#define NB      16
#define NT      480000
#define FLEN    800
#define STEP    200
#define NFRAMES 2397
#define NBINS   401

#define NKT     28                      // k-tiles of 16 bins (448 total)
#define NKS     25                      // K-chunks of 32 (800/32)
#define GX      7                       // k-column blocks (64 bins each)
#define GY      19                      // frame blocks (128 frames each)
#define NWG     (GX * GY * NB)          // 2128 = 8 * 266
#define PER_XCD (NWG / 8)               // 266
#define SIG_OFF (1u << 20)              // sig bf16 at +1MB in ws
#define WS_NEED (SIG_OFF + (size_t)NB * NT * 2)

typedef __bf16 bf16x8 __attribute__((ext_vector_type(8)));
typedef __bf16 bf16x4 __attribute__((ext_vector_type(4)));
typedef float  f32x4  __attribute__((ext_vector_type(4)));

// ---- fused prep: W frag-build (first BUILD_BLOCKS) + sig fp32->bf16 ----
#define BUILD_THREADS (NKS * NKT * 64)            // 44800
#define BUILD_BLOCKS  ((BUILD_THREADS + 255) / 256)   // 175
#define CONV_ITEMS    ((size_t)NB * NT / 4)       // 1.92M float4s
#define CONV_BLOCKS   ((int)((CONV_ITEMS + 255) / 256))

__global__ __launch_bounds__(256)
void prep_kernel(const float* __restrict__ sig, const float* __restrict__ win,
                 __bf16* __restrict__ w, __bf16* __restrict__ sigb) {
    if (blockIdx.x < BUILD_BLOCKS) {
        // W in B-fragment-linear layout: frag = ks*NKT + kt;
        // lane: col(bin) = kt*16 + (lane&15); elem j: l = ks*32 + (lane>>4)*8 + j.
        int t = blockIdx.x * 256 + threadIdx.x;
        if (t >= BUILD_THREADS) return;
        int lane = t & 63, frag = t >> 6;
        int kt = frag % NKT, ks = frag / NKT;
        int bin = kt * 16 + (lane & 15);
        int lbase = ks * 32 + (lane >> 4) * 8;
        bf16x8 o;
        #pragma unroll
        for (int j = 0; j < 8; ++j) {
            int l = lbase + j;
            int m = (bin * l) % FLEN;                 // exact reduction
            float c = cosf((float)m * -0.00785398163397448279f) * win[l];
            o[j] = (__bf16)c;
        }
        ((bf16x8*)w)[t] = o;
    } else {
        size_t i = (size_t)(blockIdx.x - BUILD_BLOCKS) * 256 + threadIdx.x;
        if (i >= CONV_ITEMS) return;
        float4 v = ((const float4*)sig)[i];
        bf16x4 o;
        o[0] = (__bf16)v.x; o[1] = (__bf16)v.y; o[2] = (__bf16)v.z; o[3] = (__bf16)v.w;
        ((bf16x4*)sigb)[i] = o;
    }
}

// ---- main: bf16 MFMA GEMM, wave tile 64f x 64k, 2 waves/block (128f x 64k) ----
__global__ __launch_bounds__(128)
void stft_mfma_kernel(const __bf16* __restrict__ sigb,
                      const __bf16* __restrict__ w,
                      float* __restrict__ out) {
    // XCD-aware swizzle: dispatch id D runs on XCD D%8; give each XCD a
    // contiguous x-major chunk so k-column blocks of a (y,b) group share L2.
    const int D = blockIdx.x + GX * (blockIdx.y + GY * blockIdx.z);
    const int P = (D % 8) * PER_XCD + (D / 8);
    const int x = P % GX;
    const int y = (P / GX) % GY;
    const int b = P / (GX * GY);

    const int lane = threadIdx.x & 63;
    const int wid  = threadIdx.x >> 6;   // 0..1
    const int f0   = y * 128 + wid * 64;
    const int kt0  = x * 4;
    const int r    = lane & 15;      // A row / C col within 16-tile
    const int h    = lane >> 4;      // K-half group 0..3

    const __bf16* sb = sigb + (size_t)b * NT;
    const bf16x8* wf = (const bf16x8*)w;

    const bf16x8* ap[4];
    #pragma unroll
    for (int m = 0; m < 4; ++m) {
        int rr = f0 + m * 16 + r;
        if (rr > NFRAMES - 1) rr = NFRAMES - 1;
        ap[m] = (const bf16x8*)(sb + (size_t)rr * STEP) + h;   // 16B aligned
    }

    f32x4 acc[4][4];
    #pragma unroll
    for (int m = 0; m < 4; ++m)
        #pragma unroll
        for (int n = 0; n < 4; ++n)
            acc[m][n] = (f32x4){0.f, 0.f, 0.f, 0.f};

    for (int ks = 0; ks < NKS; ++ks) {
        bf16x8 a0 = ap[0][ks * 4];
        bf16x8 a1 = ap[1][ks * 4];
        bf16x8 a2 = ap[2][ks * 4];
        bf16x8 a3 = ap[3][ks * 4];
        bf16x8 b0 = wf[(ks * NKT + kt0 + 0) * 64 + lane];
        bf16x8 b1 = wf[(ks * NKT + kt0 + 1) * 64 + lane];
        bf16x8 b2 = wf[(ks * NKT + kt0 + 2) * 64 + lane];
        bf16x8 b3 = wf[(ks * NKT + kt0 + 3) * 64 + lane];

        #define MM(AM, I)                                                            \
            acc[I][0] = __builtin_amdgcn_mfma_f32_16x16x32_bf16(AM, b0, acc[I][0], 0, 0, 0); \
            acc[I][1] = __builtin_amdgcn_mfma_f32_16x16x32_bf16(AM, b1, acc[I][1], 0, 0, 0); \
            acc[I][2] = __builtin_amdgcn_mfma_f32_16x16x32_bf16(AM, b2, acc[I][2], 0, 0, 0); \
            acc[I][3] = __builtin_amdgcn_mfma_f32_16x16x32_bf16(AM, b3, acc[I][3], 0, 0, 0);
        MM(a0, 0) MM(a1, 1) MM(a2, 2) MM(a3, 3)
        #undef MM
    }

    // C/D layout: col = lane&15 (bin), row = (lane>>4)*4 + reg (frame)
    const size_t ob = (size_t)b * NFRAMES;
    #pragma unroll
    for (int m = 0; m < 4; ++m) {
        int fbase = f0 + m * 16 + h * 4;
        #pragma unroll
        for (int n = 0; n < 4; ++n) {
            int k = x * 64 + n * 16 + r;
            if (k < NBINS) {
                #pragma unroll
                for (int reg = 0; reg < 4; ++reg) {
                    int f = fbase + reg;
                    if (f < NFRAMES)
                        out[(ob + f) * NBINS + k] = acc[m][n][reg];
                }
            }
        }
    }
}

// ---- fp32 fallback (proven round 10): used only if ws too small ----
#define BFT 32
#define BKT 32
#define LCH 100
#define LPAD 108
__global__ __launch_bounds__(256)
void stft_f32_kernel(const float* __restrict__ sig, const float* __restrict__ win,
                     float* __restrict__ out) {
    __shared__ float s_sig[(BFT - 1) * STEP + LCH];
    __shared__ float s_cw[BKT][LPAD];
    const int tid = threadIdx.x;
    const int k0 = blockIdx.x * BKT, f0 = blockIdx.y * BFT, b = blockIdx.z;
    const int kk = tid & 15, ff = tid >> 4;
    float r00 = 0.f, r01 = 0.f, r10 = 0.f, r11 = 0.f;
    const float* sigb = sig + (size_t)b * NT;
    for (int l0 = 0; l0 < FLEN; l0 += LCH) {
        for (int i = tid; i < (BFT - 1) * STEP + LCH; i += 256) {
            int gs = f0 * STEP + l0 + i;
            s_sig[i] = (gs < NT) ? sigb[gs] : 0.0f;
        }
        for (int i = tid; i < BKT * LCH; i += 256) {
            int kx = i / LCH, dl = i - kx * LCH, k = k0 + kx, l = l0 + dl;
            float c = 0.f;
            if (k < NBINS) {
                int m = (k * l) % FLEN;
                c = __cosf((float)m * -0.00785398163397448279f) * win[l];
            }
            s_cw[kx][dl] = c;
        }
        __syncthreads();
        for (int dl = 0; dl < LCH; dl += 4) {
            float4 a0 = *(const float4*)&s_sig[ff * STEP + dl];
            float4 a1 = *(const float4*)&s_sig[(ff + 16) * STEP + dl];
            float4 c0 = *(const float4*)&s_cw[kk][dl];
            float4 c1 = *(const float4*)&s_cw[kk + 16][dl];
            r00 = fmaf(a0.x, c0.x, r00); r00 = fmaf(a0.y, c0.y, r00);
            r00 = fmaf(a0.z, c0.z, r00); r00 = fmaf(a0.w, c0.w, r00);
            r01 = fmaf(a0.x, c1.x, r01); r01 = fmaf(a0.y, c1.y, r01);
            r01 = fmaf(a0.z, c1.z, r01); r01 = fmaf(a0.w, c1.w, r01);
            r10 = fmaf(a1.x, c0.x, r10); r10 = fmaf(a1.y, c0.y, r10);
            r10 = fmaf(a1.z, c0.z, r10); r10 = fmaf(a1.w, c0.w, r10);
            r11 = fmaf(a1.x, c1.x, r11); r11 = fmaf(a1.y, c1.y, r11);
            r11 = fmaf(a1.z, c1.z, r11); r11 = fmaf(a1.w, c1.w, r11);
        }
        __syncthreads();
    }
    const size_t ob = (size_t)b * NFRAMES;
    { int f = f0 + ff,      k = k0 + kk;      if (f < NFRAMES && k < NBINS) out[(ob + f) * NBINS + k] = r00; }
    { int f = f0 + ff,      k = k0 + kk + 16; if (f < NFRAMES && k < NBINS) out[(ob + f) * NBINS + k] = r01; }
    { int f = f0 + ff + 16, k = k0 + kk;      if (f < NFRAMES && k < NBINS) out[(ob + f) * NBINS + k] = r10; }
    { int f = f0 + ff + 16, k = k0 + kk + 16; if (f < NFRAMES && k < NBINS) out[(ob + f) * NBINS + k] = r11; }
}

extern "C" void kernel_launch(void* const* d_in, const int* in_sizes, int n_in,
                              void* d_out, int out_size, void* d_ws, size_t ws_size,
                              hipStream_t stream) {
    const float* sig = (const float*)d_in[0];
    const float* win = (const float*)d_in[1];
    float* out = (float*)d_out;

    if (ws_size >= WS_NEED) {
        __bf16* wfr    = (__bf16*)d_ws;
        __bf16* sigb16 = (__bf16*)((char*)d_ws + SIG_OFF);
        prep_kernel<<<dim3(BUILD_BLOCKS + CONV_BLOCKS), dim3(256), 0, stream>>>(sig, win, wfr, sigb16);
        dim3 grid(GX, GY, NB);   // 7 x 19 x 16 = 2128 blocks, 128 threads
        stft_mfma_kernel<<<grid, dim3(128), 0, stream>>>(sigb16, wfr, out);
    } else {
        dim3 grid((NBINS + BKT - 1) / BKT, (NFRAMES + BFT - 1) / BFT, NB);
        stft_f32_kernel<<<grid, dim3(256), 0, stream>>>(sig, win, out);
    }
}

// Round 15
// 145.085 us; speedup vs baseline: 1.0731x; 1.0731x over previous
//
#include <hip/hip_runtime.h>

// TFLite STFT as bf16 MFMA GEMM. Output: real part only,
// out[(b*2397+f)*401+k], 15,379,152 floats.
// Round 14/15: R12 shape (256thr, 4 waves x 32f x 64k, 2128 blocks,
// XCD swizzle — proven 69.7us) + B staged through double-buffered LDS:
// the 4 waves of a block share identical B fragments, so stage once per
// block (4KB/ks) instead of 4x private L2 loads. L2 traffic 1.31GB -> 0.64GB.
// Async-stage split: issue next-ks B load early, ds_write after MFMAs.

#define NB      16
#define NT      480000
#define FLEN    800
#define STEP    200
#define NFRAMES 2397
#define NBINS   401

#define NKT     28                      // k-tiles of 16 bins (448 total)
#define NKS     25                      // K-chunks of 32 (800/32)
#define GX      7                       // k-column blocks (64 bins each)
#define GY      19                      // frame blocks (128 frames each)
#define NWG     (GX * GY * NB)          // 2128 = 8 * 266
#define PER_XCD (NWG / 8)               // 266
#define SIG_OFF (1u << 20)              // sig bf16 at +1MB in ws
#define WS_NEED (SIG_OFF + (size_t)NB * NT * 2)

typedef __bf16 bf16x8 __attribute__((ext_vector_type(8)));
typedef __bf16 bf16x4 __attribute__((ext_vector_type(4)));
typedef float  f32x4  __attribute__((ext_vector_type(4)));

// ---- fused prep: W frag-build (first BUILD_BLOCKS) + sig fp32->bf16 ----
#define BUILD_THREADS (NKS * NKT * 64)                // 44800
#define BUILD_BLOCKS  ((BUILD_THREADS + 255) / 256)   // 175
#define CONV_ITEMS    ((size_t)NB * NT / 4)           // 1.92M float4s
#define CONV_BLOCKS   ((int)((CONV_ITEMS + 255) / 256))

__global__ __launch_bounds__(256)
void prep_kernel(const float* __restrict__ sig, const float* __restrict__ win,
                 __bf16* __restrict__ w, __bf16* __restrict__ sigb) {
    if (blockIdx.x < BUILD_BLOCKS) {
        // W in B-fragment-linear layout: frag = ks*NKT + kt;
        // lane: col(bin) = kt*16 + (lane&15); elem j: l = ks*32 + (lane>>4)*8 + j.
        int t = blockIdx.x * 256 + threadIdx.x;
        if (t >= BUILD_THREADS) return;
        int lane = t & 63, frag = t >> 6;
        int kt = frag % NKT, ks = frag / NKT;
        int bin = kt * 16 + (lane & 15);
        int lbase = ks * 32 + (lane >> 4) * 8;
        bf16x8 o;
        #pragma unroll
        for (int j = 0; j < 8; ++j) {
            int l = lbase + j;
            int m = (bin * l) % FLEN;                 // exact reduction
            float c = cosf((float)m * -0.00785398163397448279f) * win[l];
            o[j] = (__bf16)c;
        }
        ((bf16x8*)w)[t] = o;
    } else {
        size_t i = (size_t)(blockIdx.x - BUILD_BLOCKS) * 256 + threadIdx.x;
        if (i >= CONV_ITEMS) return;
        float4 v = ((const float4*)sig)[i];
        bf16x4 o;
        o[0] = (__bf16)v.x; o[1] = (__bf16)v.y; o[2] = (__bf16)v.z; o[3] = (__bf16)v.w;
        ((bf16x4*)sigb)[i] = o;
    }
}

// ---- main: bf16 MFMA GEMM, 4 waves x (32f x 64k), block 128f x 64k ----
__global__ __launch_bounds__(256)
void stft_mfma_kernel(const __bf16* __restrict__ sigb,
                      const __bf16* __restrict__ w,
                      float* __restrict__ out) {
    __shared__ bf16x8 ldsb[2][4][64];   // [buf][kt][lane], 16B/elem = 8KB

    // XCD-aware swizzle (bijective: 2128 = 8*266): k-column blocks of a
    // (y,b) group land on one XCD -> A re-reads are L2 hits.
    const int D = blockIdx.x + GX * (blockIdx.y + GY * blockIdx.z);
    const int P = (D % 8) * PER_XCD + (D / 8);
    const int x = P % GX;
    const int y = (P / GX) % GY;
    const int b = P / (GX * GY);

    const int lane = threadIdx.x & 63;
    const int wid  = threadIdx.x >> 6;   // 0..3
    const int f0   = y * 128 + wid * 32;
    const int kt0  = x * 4;
    const int r    = lane & 15;      // A row / C col within 16-tile
    const int h    = lane >> 4;      // K-half group 0..3

    const __bf16* sb = sigb + (size_t)b * NT;
    const bf16x8* wf = (const bf16x8*)w;

    const bf16x8* ap0; const bf16x8* ap1;
    {
        int r0 = f0 + r;      if (r0 > NFRAMES - 1) r0 = NFRAMES - 1;
        int r1 = f0 + 16 + r; if (r1 > NFRAMES - 1) r1 = NFRAMES - 1;
        ap0 = (const bf16x8*)(sb + (size_t)r0 * STEP) + h;   // 16B aligned
        ap1 = (const bf16x8*)(sb + (size_t)r1 * STEP) + h;
    }

    f32x4 acc[2][4];
    #pragma unroll
    for (int m = 0; m < 2; ++m)
        #pragma unroll
        for (int n = 0; n < 4; ++n)
            acc[m][n] = (f32x4){0.f, 0.f, 0.f, 0.f};

    // prologue: stage ks=0 B into buf 0 (wave wid owns kt slot wid)
    ldsb[0][wid][lane] = wf[(size_t)(0 * NKT + kt0 + wid) * 64 + lane];
    __syncthreads();

    int cur = 0;
    for (int ks = 0; ks < NKS; ++ks) {
        // T14 split: issue next-ks B global load NOW (lands during MFMAs)
        bf16x8 bstage;
        bool do_stage = (ks + 1 < NKS);
        if (do_stage)
            bstage = wf[(size_t)((ks + 1) * NKT + kt0 + wid) * 64 + lane];

        bf16x8 a0 = ap0[ks * 4];
        bf16x8 a1 = ap1[ks * 4];
        bf16x8 b0 = ldsb[cur][0][lane];
        bf16x8 b1 = ldsb[cur][1][lane];
        bf16x8 b2 = ldsb[cur][2][lane];
        bf16x8 b3 = ldsb[cur][3][lane];

        #define MM(AM, I)                                                            \
            acc[I][0] = __builtin_amdgcn_mfma_f32_16x16x32_bf16(AM, b0, acc[I][0], 0, 0, 0); \
            acc[I][1] = __builtin_amdgcn_mfma_f32_16x16x32_bf16(AM, b1, acc[I][1], 0, 0, 0); \
            acc[I][2] = __builtin_amdgcn_mfma_f32_16x16x32_bf16(AM, b2, acc[I][2], 0, 0, 0); \
            acc[I][3] = __builtin_amdgcn_mfma_f32_16x16x32_bf16(AM, b3, acc[I][3], 0, 0, 0);
        MM(a0, 0) MM(a1, 1)
        #undef MM

        // write next-ks B into the other buffer (after MFMAs, before barrier)
        if (do_stage)
            ldsb[cur ^ 1][wid][lane] = bstage;
        __syncthreads();
        cur ^= 1;
    }

    // C/D layout: col = lane&15 (bin), row = (lane>>4)*4 + reg (frame)
    const size_t ob = (size_t)b * NFRAMES;
    #pragma unroll
    for (int m = 0; m < 2; ++m) {
        int fbase = f0 + m * 16 + h * 4;
        #pragma unroll
        for (int n = 0; n < 4; ++n) {
            int k = x * 64 + n * 16 + r;
            if (k < NBINS) {
                #pragma unroll
                for (int reg = 0; reg < 4; ++reg) {
                    int f = fbase + reg;
                    if (f < NFRAMES)
                        out[(ob + f) * NBINS + k] = acc[m][n][reg];
                }
            }
        }
    }
}

// ---- fp32 fallback (proven round 10): used only if ws too small ----
#define BFT 32
#define BKT 32
#define LCH 100
#define LPAD 108
__global__ __launch_bounds__(256)
void stft_f32_kernel(const float* __restrict__ sig, const float* __restrict__ win,
                     float* __restrict__ out) {
    __shared__ float s_sig[(BFT - 1) * STEP + LCH];
    __shared__ float s_cw[BKT][LPAD];
    const int tid = threadIdx.x;
    const int k0 = blockIdx.x * BKT, f0 = blockIdx.y * BFT, b = blockIdx.z;
    const int kk = tid & 15, ff = tid >> 4;
    float r00 = 0.f, r01 = 0.f, r10 = 0.f, r11 = 0.f;
    const float* sigb = sig + (size_t)b * NT;
    for (int l0 = 0; l0 < FLEN; l0 += LCH) {
        for (int i = tid; i < (BFT - 1) * STEP + LCH; i += 256) {
            int gs = f0 * STEP + l0 + i;
            s_sig[i] = (gs < NT) ? sigb[gs] : 0.0f;
        }
        for (int i = tid; i < BKT * LCH; i += 256) {
            int kx = i / LCH, dl = i - kx * LCH, k = k0 + kx, l = l0 + dl;
            float c = 0.f;
            if (k < NBINS) {
                int m = (k * l) % FLEN;
                c = __cosf((float)m * -0.00785398163397448279f) * win[l];
            }
            s_cw[kx][dl] = c;
        }
        __syncthreads();
        for (int dl = 0; dl < LCH; dl += 4) {
            float4 a0 = *(const float4*)&s_sig[ff * STEP + dl];
            float4 a1 = *(const float4*)&s_sig[(ff + 16) * STEP + dl];
            float4 c0 = *(const float4*)&s_cw[kk][dl];
            float4 c1 = *(const float4*)&s_cw[kk + 16][dl];
            r00 = fmaf(a0.x, c0.x, r00); r00 = fmaf(a0.y, c0.y, r00);
            r00 = fmaf(a0.z, c0.z, r00); r00 = fmaf(a0.w, c0.w, r00);
            r01 = fmaf(a0.x, c1.x, r01); r01 = fmaf(a0.y, c1.y, r01);
            r01 = fmaf(a0.z, c1.z, r01); r01 = fmaf(a0.w, c1.w, r01);
            r10 = fmaf(a1.x, c0.x, r10); r10 = fmaf(a1.y, c0.y, r10);
            r10 = fmaf(a1.z, c0.z, r10); r10 = fmaf(a1.w, c0.w, r10);
            r11 = fmaf(a1.x, c1.x, r11); r11 = fmaf(a1.y, c1.y, r11);
            r11 = fmaf(a1.z, c1.z, r11); r11 = fmaf(a1.w, c1.w, r11);
        }
        __syncthreads();
    }
    const size_t ob = (size_t)b * NFRAMES;
    { int f = f0 + ff,      k = k0 + kk;      if (f < NFRAMES && k < NBINS) out[(ob + f) * NBINS + k] = r00; }
    { int f = f0 + ff,      k = k0 + kk + 16; if (f < NFRAMES && k < NBINS) out[(ob + f) * NBINS + k] = r01; }
    { int f = f0 + ff + 16, k = k0 + kk;      if (f < NFRAMES && k < NBINS) out[(ob + f) * NBINS + k] = r10; }
    { int f = f0 + ff + 16, k = k0 + kk + 16; if (f < NFRAMES && k < NBINS) out[(ob + f) * NBINS + k] = r11; }
}

extern "C" void kernel_launch(void* const* d_in, const int* in_sizes, int n_in,
                              void* d_out, int out_size, void* d_ws, size_t ws_size,
                              hipStream_t stream) {
    const float* sig = (const float*)d_in[0];
    const float* win = (const float*)d_in[1];
    float* out = (float*)d_out;

    if (ws_size >= WS_NEED) {
        __bf16* wfr    = (__bf16*)d_ws;
        __bf16* sigb16 = (__bf16*)((char*)d_ws + SIG_OFF);
        prep_kernel<<<dim3(BUILD_BLOCKS + CONV_BLOCKS), dim3(256), 0, stream>>>(sig, win, wfr, sigb16);
        dim3 grid(GX, GY, NB);   // 7 x 19 x 16 = 2128 blocks, 256 threads
        stft_mfma_kernel<<<grid, dim3(256), 0, stream>>>(sigb16, wfr, out);
    } else {
        dim3 grid((NBINS + BKT - 1) / BKT, (NFRAMES + BFT - 1) / BFT, NB);
        stft_f32_kernel<<<grid, dim3(256), 0, stream>>>(sig, win, out);
    }
}